// Round 13
// baseline (120.777 us; speedup 1.0000x reference)
//
#include <hip/hip_runtime.h>
#include <hip/hip_bf16.h>
#include <math.h>

#define M_ROWS 65536
#define NSPLINE 32
#define BM 64            // rows per block (R14-proven)
#define WROWS 16         // rows per wave
#define GROUP 4          // splines per iteration (one per quad q)
#define NITER (NSPLINE / GROUP)   // 8 groups per wave
#define NTILE 9          // ceil(33 params / 4-per-lane) MFMA tiles per group
#define WB_ELEMS (NITER * NTILE * 2 * 64 * 8)   // 73728 fp16 = 144 KiB
#define LOG2E 1.4426950408889634f
#define LN2   0.69314718055994531f

typedef __attribute__((ext_vector_type(8))) _Float16 half8;
typedef __attribute__((ext_vector_type(4))) float floatx4;

// R21 softplus: poly with the +0.001 FOLDED into the ln2 constant.
// The |t|>1.1 exact-fallback lives in ONE batched cold guard in the kernel
// body (straight-line recompute of all 17 when triggered, P ~ 0.3%), so the
// hot path is a single basic block per iteration.
__device__ __forceinline__ float softplus_poly(float t) {
    float u = t * t;
    float p = fmaf(u, -2.6352e-5f, 3.4722222e-4f);
    p = fmaf(u, p, -5.2083333e-3f);
    p = fmaf(u, p, 0.125f);
    p = fmaf(u, p, 0.69414718f);       // ln2 + 0.001 folded
    return fmaf(t, 0.5f, p);
}

// ---------------------------------------------------------------------------
// R14-proven pack + exp2 pre-scale (R20): WIDTH columns (param 17..32)
// scaled by log2(e) at pack time -> kernel softmax-exp is raw v_exp_f32.
// m-mapping per tile tau:
//   m = (spline-sub q_m)*4 + r  ->  column (spline = g*4+q_m, param = tau*4+r)
// A-fragment: lane L, elem j: m = L&15, k = half*32 + (L>>4)*8 + j
//   k<48: W[k][col]; k==48: bias (paired with B=1.0); else 0.
// ---------------------------------------------------------------------------
__global__ void pack_W(const float* __restrict__ W, const float* __restrict__ b,
                       _Float16* __restrict__ WH) {
    int idx = blockIdx.x * 256 + threadIdx.x;     // < 73728
    int j    = idx & 7;
    int lane = (idx >> 3) & 63;
    int half = (idx >> 9) & 1;
    int tile = idx >> 10;        // 0..71 = g*NTILE + tau
    int tau  = tile % NTILE;
    int g    = tile / NTILE;
    int m  = lane & 15;
    int k  = half * 32 + ((lane >> 4) << 3) + j;
    int spline = g * 4 + (m >> 2);
    int param  = tau * 4 + (m & 3);
    float v = 0.0f;
    if (param < 33 && k <= 48) {
        int col = spline * 33 + param;
        v = (k < 48) ? W[k * 1056 + col] : b[col];
        if (param >= 17) v *= LOG2E;              // width columns: exp -> exp2
    }
    WH[idx] = (_Float16)v;
}

// pv[p] lives in the MFMA accumulators; indices are all compile-time.
#define PV(p) (acc[(p) >> 2][(p) & 3])

// ---------------------------------------------------------------------------
// R21b = R20 (proven 43.8us fused) + arithmetic slimming:
//  - softplus 0.001-fold into the poly constant (-17 adds/task)
//  - ONE batched cold fallback guard per iteration (tree-max of |t|^2 vs
//    1.21) with a STRAIGHT-LINE all-17 exact recompute when taken
//    (P ~0.3%/wave-iter; exactness preserved; hot path = single BB).
//    [R21's nested per-element ifs inside the cold block removed -- two
//    consecutive container failures on that source; this de-risks the only
//    structurally-novel control flow while keeping the experiment.]
//  - tree-ordered sew reduction (same op count, dep depth 64->16cy)
// Empirical law: scheduling interventions lose (6/6); arithmetic deletions
// pay proportionally (R20: -55 ops -> -3.5us). This deletes ~35 more.
// ---------------------------------------------------------------------------
__global__ void __launch_bounds__(256) fused_kernel(
    const float* __restrict__ z, const float* __restrict__ c,
    const _Float16* __restrict__ WH, float* __restrict__ out)
{
    const int tid  = threadIdx.x;
    const int w    = tid >> 6;
    const int lane = tid & 63;
    const int q    = lane >> 4;        // quad 0..3 = spline-sub within group
    const int cc   = lane & 15;        // row within wave
    const int row_base = blockIdx.x * BM + w * WROWS;

    // ---- z2 passthrough: out[:, :32] = z[:, 32:64] for this wave's rows ----
    #pragma unroll
    for (int it = 0; it < 2; ++it) {
        int idx = it * 64 + lane;                 // 0..127 = 16 rows x 8 float4
        int rr  = row_base + (idx >> 3);
        int v4  = idx & 7;
        float4 val = *(const float4*)(z + (size_t)rr * 64 + 32 + v4 * 4);
        *(float4*)(out + (size_t)rr * 64 + v4 * 4) = val;
    }

    // ---- z2c fragments (fp16, persist): the B operand ---------------------
    // B[k=(q*8+j)][n=cc] = z2c[row cc][k]
    half8 a0, a1;
    {
        const float* zr = z + (size_t)(row_base + cc) * 64 + 32;
        float4 v0 = *(const float4*)(zr + q * 8);
        float4 v1 = *(const float4*)(zr + q * 8 + 4);
        a0[0]=(_Float16)v0.x; a0[1]=(_Float16)v0.y;
        a0[2]=(_Float16)v0.z; a0[3]=(_Float16)v0.w;
        a0[4]=(_Float16)v1.x; a0[5]=(_Float16)v1.y;
        a0[6]=(_Float16)v1.z; a0[7]=(_Float16)v1.w;
        if (q < 2) {
            const float* cr = c + (size_t)(row_base + cc) * 16 + q * 8;
            float4 u0 = *(const float4*)cr;
            float4 u1 = *(const float4*)(cr + 4);
            a1[0]=(_Float16)u0.x; a1[1]=(_Float16)u0.y;
            a1[2]=(_Float16)u0.z; a1[3]=(_Float16)u0.w;
            a1[4]=(_Float16)u1.x; a1[5]=(_Float16)u1.y;
            a1[6]=(_Float16)u1.z; a1[7]=(_Float16)u1.w;
        } else {
            #pragma unroll
            for (int j = 0; j < 8; ++j) a1[j] = (_Float16)0.0f;
            if (q == 2) a1[0] = (_Float16)1.0f;   // k=48 bias row
        }
    }

    // z1 base for this lane's spline inputs: z[row cc][n = g*4 + q]
    const float* z1p = z + (size_t)(row_base + cc) * 64 + q;

    float ld_acc = 0.0f;   // accumulates log2 terms; scaled once at the end

    #pragma unroll 1
    for (int g = 0; g < NITER; ++g) {
        const float in = z1p[g * 4];        // hot L1 line

        // ---- GEMM: 9 tiles x (K=32 + K=16+bias) -> pv in registers --------
        floatx4 acc[NTILE];
        const half8* base = (const half8*)WH + (size_t)g * (NTILE * 2 * 64) + lane;
        #pragma unroll
        for (int t = 0; t < NTILE; ++t) {
            half8 w0 = base[(t * 2 + 0) * 64];
            half8 w1 = base[(t * 2 + 1) * 64];
            floatx4 a = {0.f, 0.f, 0.f, 0.f};
            a = __builtin_amdgcn_mfma_f32_16x16x32_f16(w0, a0, a, 0, 0, 0);
            a = __builtin_amdgcn_mfma_f32_16x16x32_f16(w1, a1, a, 0, 0, 0);
            acc[t] = a;
        }
        // lane (q,cc) now holds PV(p) = y[row cc][spline g*4+q][param p]
        // (width params 17..32 pre-scaled by log2e).

        // ---- spline on registers -----------------------------------------
        const int n = g * GROUP + q;

        // widths: exp2 + TREE-ordered sum (same 15 adds, depth 64->16cy)
        float wd[16];
        #pragma unroll
        for (int i = 0; i < 16; ++i)
            wd[i] = __builtin_amdgcn_exp2f(PV(17 + i));   // raw v_exp_f32
        float s8[8];
        #pragma unroll
        for (int j = 0; j < 8; ++j) s8[j] = wd[2 * j] + wd[2 * j + 1];
        float s4a = s8[0] + s8[1], s4b = s8[2] + s8[3];
        float s4c = s8[4] + s8[5], s4d = s8[6] + s8[7];
        const float sew = (s4a + s4b) + (s4c + s4d);
        const float inv_sew = 0.984f * __builtin_amdgcn_rcpf(sew);
        #pragma unroll
        for (int i = 0; i < 16; ++i) wd[i] = 0.001f + wd[i] * inv_sew;

        // heights: branch-free poly (0.001 folded); one batched cold guard
        float hp[17];
        float tmax = 0.0f;
        #pragma unroll
        for (int i = 0; i < 17; ++i) {
            float t = PV(i);
            hp[i] = softplus_poly(t);
            tmax = fmaxf(tmax, t * t);
        }
        if (tmax > 1.21f) {                 // cold (~0.3%): exact all-17
            #pragma unroll
            for (int i = 0; i < 17; ++i)
                hp[i] = log1pf(__expf(PV(i))) + 0.001f;
        }

        // S = sum (hp[i]+hp[i+1])*wd[i] = 2*area_pre; u = h_norm/2
        float S = 0.f;
        #pragma unroll
        for (int i = 0; i < 16; ++i) S = fmaf(hp[i] + hp[i + 1], wd[i], S);
        const float inv2 = 0.999f * __builtin_amdgcn_rcpf(S);
        float u[17];
        #pragma unroll
        for (int i = 0; i < 17; ++i) u[i] = fmaf(hp[i], inv2, 0.0005f);

        // scan: cdf accumulates (u+u')*wd == (h+h')*0.5*wd (normalized)
        float loc = 0.f, cdfl = 0.f;
        float sel_loc = 0.f, sel_w = wd[0], sel_cdf = 0.f;
        float sel_lu = u[0], sel_ru = u[1];
        #pragma unroll
        for (int bn = 1; bn < 16; ++bn) {
            cdfl = fmaf(u[bn - 1] + u[bn], wd[bn - 1], cdfl);
            loc += wd[bn - 1];
            if (in >= loc) {                        // monotone: last true wins
                sel_loc = loc; sel_w = wd[bn]; sel_cdf = cdfl;
                sel_lu = u[bn]; sel_ru = u[bn + 1];
            }
        }

        const float alpha = (in - sel_loc) * __builtin_amdgcn_rcpf(sel_w);
        const float du    = sel_ru - sel_lu;        // = dh/2
        const float lw    = sel_lu * sel_w;         // = lh*w/2
        // o = (0.5*dh*w)*a^2 + (lh*w)*a + cdf = ((du*w)*a + 2*lw)*a + cdf
        float o = fmaf(fmaf(du * sel_w, alpha, lw + lw), alpha, sel_cdf);
        o = fminf(fmaxf(o, 0.0f), 1.0f);
        out[(size_t)(row_base + cc) * 64 + 32 + n] = o;
        // ln(a*dh + lh) = LN2*(1 + log2(a*du + lu)); defer scale+offset
        ld_acc += __builtin_amdgcn_logf(fmaf(alpha, du, sel_lu));
    }

    // ---- logdet: lanes {cc, cc+16, cc+32, cc+48} hold row cc's partials ---
    ld_acc += __shfl_down(ld_acc, 32, 64);
    ld_acc += __shfl_down(ld_acc, 16, 64);
    if (q == 0)   // 32 log2-terms: ln2*(sum + 32)
        out[(size_t)M_ROWS * 64 + row_base + cc] =
            fmaf(ld_acc, LN2, 32.0f * LN2);
}

extern "C" void kernel_launch(void* const* d_in, const int* in_sizes, int n_in,
                              void* d_out, int out_size, void* d_ws, size_t ws_size,
                              hipStream_t stream) {
    const float* c = (const float*)d_in[0];   // (M, 16)
    const float* z = (const float*)d_in[1];   // (M, 64)
    const float* W = (const float*)d_in[2];   // (48, 1056)
    const float* b = (const float*)d_in[3];   // (1056,)
    float* out = (float*)d_out;               // M*64 (x) then M (logdet)
    _Float16* WH = (_Float16*)d_ws;           // 73728 fp16 = 144 KiB

    pack_W<<<WB_ELEMS / 256, 256, 0, stream>>>(W, b, WH);
    fused_kernel<<<M_ROWS / BM, 256, 0, stream>>>(z, c, WH, out);
}

// Round 14
// 106.601 us; speedup vs baseline: 1.1330x; 1.1330x over previous
//
#include <hip/hip_runtime.h>
#include <hip/hip_bf16.h>
#include <math.h>

#define M_ROWS 65536
#define NSPLINE 32
#define BM 64            // rows per block (R14-proven)
#define WROWS 16         // rows per wave
#define GROUP 4          // splines per iteration (one per quad q)
#define NITER (NSPLINE / GROUP)   // 8 groups per wave
#define NTILE 9          // ceil(33 params / 4-per-lane) MFMA tiles per group
#define WB_ELEMS (NITER * NTILE * 2 * 64 * 8)   // 73728 fp16 = 144 KiB
#define LOG2E 1.4426950408889634f
#define LN2   0.69314718055994531f

typedef __attribute__((ext_vector_type(8))) _Float16 half8;
typedef __attribute__((ext_vector_type(4))) float floatx4;

// R22 softplus: R20's per-element branch structure (PROVEN: R21b's batched
// guard regressed 10us -- it kept all 9 accs live across a mid-iteration
// serializing branch; 17 independent micro-branches schedule better) with
// the +0.001 folded into the poly's ln2 constant (-17 adds/task; fallback
// carries it explicitly). Fallback is ~5-sigma rare; exact.
__device__ __forceinline__ float softplus_fast(float t) {
    float u = t * t;
    if (u > 1.21f) return log1pf(__expf(t)) + 0.001f;   // rare, exact
    float p = fmaf(u, -2.6352e-5f, 3.4722222e-4f);
    p = fmaf(u, p, -5.2083333e-3f);
    p = fmaf(u, p, 0.125f);
    p = fmaf(u, p, 0.69414718f);       // ln2 + 0.001 folded
    return fmaf(t, 0.5f, p);
}

// ---------------------------------------------------------------------------
// R14-proven pack + exp2 pre-scale (R20): WIDTH columns (param 17..32)
// scaled by log2(e) at pack time -> kernel softmax-exp is raw v_exp_f32.
// m-mapping per tile tau:
//   m = (spline-sub q_m)*4 + r  ->  column (spline = g*4+q_m, param = tau*4+r)
// A-fragment: lane L, elem j: m = L&15, k = half*32 + (L>>4)*8 + j
//   k<48: W[k][col]; k==48: bias (paired with B=1.0); else 0.
// ---------------------------------------------------------------------------
__global__ void pack_W(const float* __restrict__ W, const float* __restrict__ b,
                       _Float16* __restrict__ WH) {
    int idx = blockIdx.x * 256 + threadIdx.x;     // < 73728
    int j    = idx & 7;
    int lane = (idx >> 3) & 63;
    int half = (idx >> 9) & 1;
    int tile = idx >> 10;        // 0..71 = g*NTILE + tau
    int tau  = tile % NTILE;
    int g    = tile / NTILE;
    int m  = lane & 15;
    int k  = half * 32 + ((lane >> 4) << 3) + j;
    int spline = g * 4 + (m >> 2);
    int param  = tau * 4 + (m & 3);
    float v = 0.0f;
    if (param < 33 && k <= 48) {
        int col = spline * 33 + param;
        v = (k < 48) ? W[k * 1056 + col] : b[col];
        if (param >= 17) v *= LOG2E;              // width columns: exp -> exp2
    }
    WH[idx] = (_Float16)v;
}

// pv[p] lives in the MFMA accumulators; indices are all compile-time.
#define PV(p) (acc[(p) >> 2][(p) & 3])

// ---------------------------------------------------------------------------
// R22 = R20 (proven 43.8us fused) + the two control-flow-neutral deltas
// unbundled from R21b (whose batched guard caused the 10us regression):
//  - softplus 0.001-fold (-17 adds/task), per-element branches KEPT
//  - tree-ordered sew reduction (same ops, dep depth 64->16cy)
// Empirical laws: scheduling interventions lose (7/7); arithmetic deletions
// pay proportionally (R20: -55 ops -> -3.5us); macro-branches serialize
// (R21b). If this round shows no gain, the structure is at its floor.
// ---------------------------------------------------------------------------
__global__ void __launch_bounds__(256) fused_kernel(
    const float* __restrict__ z, const float* __restrict__ c,
    const _Float16* __restrict__ WH, float* __restrict__ out)
{
    const int tid  = threadIdx.x;
    const int w    = tid >> 6;
    const int lane = tid & 63;
    const int q    = lane >> 4;        // quad 0..3 = spline-sub within group
    const int cc   = lane & 15;        // row within wave
    const int row_base = blockIdx.x * BM + w * WROWS;

    // ---- z2 passthrough: out[:, :32] = z[:, 32:64] for this wave's rows ----
    #pragma unroll
    for (int it = 0; it < 2; ++it) {
        int idx = it * 64 + lane;                 // 0..127 = 16 rows x 8 float4
        int rr  = row_base + (idx >> 3);
        int v4  = idx & 7;
        float4 val = *(const float4*)(z + (size_t)rr * 64 + 32 + v4 * 4);
        *(float4*)(out + (size_t)rr * 64 + v4 * 4) = val;
    }

    // ---- z2c fragments (fp16, persist): the B operand ---------------------
    // B[k=(q*8+j)][n=cc] = z2c[row cc][k]
    half8 a0, a1;
    {
        const float* zr = z + (size_t)(row_base + cc) * 64 + 32;
        float4 v0 = *(const float4*)(zr + q * 8);
        float4 v1 = *(const float4*)(zr + q * 8 + 4);
        a0[0]=(_Float16)v0.x; a0[1]=(_Float16)v0.y;
        a0[2]=(_Float16)v0.z; a0[3]=(_Float16)v0.w;
        a0[4]=(_Float16)v1.x; a0[5]=(_Float16)v1.y;
        a0[6]=(_Float16)v1.z; a0[7]=(_Float16)v1.w;
        if (q < 2) {
            const float* cr = c + (size_t)(row_base + cc) * 16 + q * 8;
            float4 u0 = *(const float4*)cr;
            float4 u1 = *(const float4*)(cr + 4);
            a1[0]=(_Float16)u0.x; a1[1]=(_Float16)u0.y;
            a1[2]=(_Float16)u0.z; a1[3]=(_Float16)u0.w;
            a1[4]=(_Float16)u1.x; a1[5]=(_Float16)u1.y;
            a1[6]=(_Float16)u1.z; a1[7]=(_Float16)u1.w;
        } else {
            #pragma unroll
            for (int j = 0; j < 8; ++j) a1[j] = (_Float16)0.0f;
            if (q == 2) a1[0] = (_Float16)1.0f;   // k=48 bias row
        }
    }

    // z1 base for this lane's spline inputs: z[row cc][n = g*4 + q]
    const float* z1p = z + (size_t)(row_base + cc) * 64 + q;

    float ld_acc = 0.0f;   // accumulates log2 terms; scaled once at the end

    #pragma unroll 1
    for (int g = 0; g < NITER; ++g) {
        const float in = z1p[g * 4];        // hot L1 line

        // ---- GEMM: 9 tiles x (K=32 + K=16+bias) -> pv in registers --------
        floatx4 acc[NTILE];
        const half8* base = (const half8*)WH + (size_t)g * (NTILE * 2 * 64) + lane;
        #pragma unroll
        for (int t = 0; t < NTILE; ++t) {
            half8 w0 = base[(t * 2 + 0) * 64];
            half8 w1 = base[(t * 2 + 1) * 64];
            floatx4 a = {0.f, 0.f, 0.f, 0.f};
            a = __builtin_amdgcn_mfma_f32_16x16x32_f16(w0, a0, a, 0, 0, 0);
            a = __builtin_amdgcn_mfma_f32_16x16x32_f16(w1, a1, a, 0, 0, 0);
            acc[t] = a;
        }
        // lane (q,cc) now holds PV(p) = y[row cc][spline g*4+q][param p]
        // (width params 17..32 pre-scaled by log2e).

        // ---- spline on registers -----------------------------------------
        const int n = g * GROUP + q;

        // widths: exp2 + TREE-ordered sum (same 15 adds, depth 64->16cy)
        float wd[16];
        #pragma unroll
        for (int i = 0; i < 16; ++i)
            wd[i] = __builtin_amdgcn_exp2f(PV(17 + i));   // raw v_exp_f32
        float s8[8];
        #pragma unroll
        for (int j = 0; j < 8; ++j) s8[j] = wd[2 * j] + wd[2 * j + 1];
        float s4a = s8[0] + s8[1], s4b = s8[2] + s8[3];
        float s4c = s8[4] + s8[5], s4d = s8[6] + s8[7];
        const float sew = (s4a + s4b) + (s4c + s4d);
        const float inv_sew = 0.984f * __builtin_amdgcn_rcpf(sew);
        #pragma unroll
        for (int i = 0; i < 16; ++i) wd[i] = 0.001f + wd[i] * inv_sew;

        // heights: R20-structure per-element softplus, 0.001 pre-folded
        float hp[17];
        #pragma unroll
        for (int i = 0; i < 17; ++i)
            hp[i] = softplus_fast(PV(i));

        // S = sum (hp[i]+hp[i+1])*wd[i] = 2*area_pre; u = h_norm/2
        float S = 0.f;
        #pragma unroll
        for (int i = 0; i < 16; ++i) S = fmaf(hp[i] + hp[i + 1], wd[i], S);
        const float inv2 = 0.999f * __builtin_amdgcn_rcpf(S);
        float u[17];
        #pragma unroll
        for (int i = 0; i < 17; ++i) u[i] = fmaf(hp[i], inv2, 0.0005f);

        // scan: cdf accumulates (u+u')*wd == (h+h')*0.5*wd (normalized)
        float loc = 0.f, cdfl = 0.f;
        float sel_loc = 0.f, sel_w = wd[0], sel_cdf = 0.f;
        float sel_lu = u[0], sel_ru = u[1];
        #pragma unroll
        for (int bn = 1; bn < 16; ++bn) {
            cdfl = fmaf(u[bn - 1] + u[bn], wd[bn - 1], cdfl);
            loc += wd[bn - 1];
            if (in >= loc) {                        // monotone: last true wins
                sel_loc = loc; sel_w = wd[bn]; sel_cdf = cdfl;
                sel_lu = u[bn]; sel_ru = u[bn + 1];
            }
        }

        const float alpha = (in - sel_loc) * __builtin_amdgcn_rcpf(sel_w);
        const float du    = sel_ru - sel_lu;        // = dh/2
        const float lw    = sel_lu * sel_w;         // = lh*w/2
        // o = (0.5*dh*w)*a^2 + (lh*w)*a + cdf = ((du*w)*a + 2*lw)*a + cdf
        float o = fmaf(fmaf(du * sel_w, alpha, lw + lw), alpha, sel_cdf);
        o = fminf(fmaxf(o, 0.0f), 1.0f);
        out[(size_t)(row_base + cc) * 64 + 32 + n] = o;
        // ln(a*dh + lh) = LN2*(1 + log2(a*du + lu)); defer scale+offset
        ld_acc += __builtin_amdgcn_logf(fmaf(alpha, du, sel_lu));
    }

    // ---- logdet: lanes {cc, cc+16, cc+32, cc+48} hold row cc's partials ---
    ld_acc += __shfl_down(ld_acc, 32, 64);
    ld_acc += __shfl_down(ld_acc, 16, 64);
    if (q == 0)   // 32 log2-terms: ln2*(sum + 32)
        out[(size_t)M_ROWS * 64 + row_base + cc] =
            fmaf(ld_acc, LN2, 32.0f * LN2);
}

extern "C" void kernel_launch(void* const* d_in, const int* in_sizes, int n_in,
                              void* d_out, int out_size, void* d_ws, size_t ws_size,
                              hipStream_t stream) {
    const float* c = (const float*)d_in[0];   // (M, 16)
    const float* z = (const float*)d_in[1];   // (M, 64)
    const float* W = (const float*)d_in[2];   // (48, 1056)
    const float* b = (const float*)d_in[3];   // (1056,)
    float* out = (float*)d_out;               // M*64 (x) then M (logdet)
    _Float16* WH = (_Float16*)d_ws;           // 73728 fp16 = 144 KiB

    pack_W<<<WB_ELEMS / 256, 256, 0, stream>>>(W, b, WH);
    fused_kernel<<<M_ROWS / BM, 256, 0, stream>>>(z, c, WH, out);
}

// Round 15
// 106.446 us; speedup vs baseline: 1.1346x; 1.0015x over previous
//
#include <hip/hip_runtime.h>
#include <hip/hip_bf16.h>
#include <math.h>

#define M_ROWS 65536
#define NSPLINE 32
#define BM 64            // rows per block (R14-proven)
#define WROWS 16         // rows per wave
#define GROUP 4          // splines per iteration (one per quad q)
#define NITER (NSPLINE / GROUP)   // 8 groups per wave
#define NTILE 9          // ceil(33 params / 4-per-lane) MFMA tiles per group
#define WB_ELEMS (NITER * NTILE * 2 * 64 * 8)   // 73728 fp16 = 144 KiB
#define LOG2E 1.4426950408889634f
#define LN2   0.69314718055994531f

typedef __attribute__((ext_vector_type(8))) _Float16 half8;
typedef __attribute__((ext_vector_type(4))) float floatx4;
typedef __attribute__((ext_vector_type(2))) float f32x2;

// R23: 2-way PACKED softplus (v_pk_fma_f32 path). Poly math identical to
// R22; the rare exact fallback stays as per-element scalar micro-branches
// (R21b proved micro-branches schedule fine, macro-branches serialize).
__device__ __forceinline__ f32x2 softplus2(f32x2 t) {
    f32x2 u = t * t;
    f32x2 p = u * -2.6352e-5f + 3.4722222e-4f;   // contracts to pk_fma
    p = u * p + -5.2083333e-3f;
    p = u * p + 0.125f;
    p = u * p + 0.69414718f;                     // ln2 + 0.001 folded
    f32x2 r = t * 0.5f + p;
    if (u.x > 1.21f) r.x = log1pf(__expf(t.x)) + 0.001f;   // ~5-sigma rare
    if (u.y > 1.21f) r.y = log1pf(__expf(t.y)) + 0.001f;
    return r;
}
__device__ __forceinline__ float softplus1(float t) {
    float u = t * t;
    if (u > 1.21f) return log1pf(__expf(t)) + 0.001f;
    float p = fmaf(u, -2.6352e-5f, 3.4722222e-4f);
    p = fmaf(u, p, -5.2083333e-3f);
    p = fmaf(u, p, 0.125f);
    p = fmaf(u, p, 0.69414718f);
    return fmaf(t, 0.5f, p);
}

// ---------------------------------------------------------------------------
// R14-proven pack + exp2 pre-scale (R20): WIDTH columns (param 17..32)
// scaled by log2(e) at pack time -> kernel softmax-exp is raw v_exp_f32.
// m-mapping per tile tau:
//   m = (spline-sub q_m)*4 + r  ->  column (spline = g*4+q_m, param = tau*4+r)
// A-fragment: lane L, elem j: m = L&15, k = half*32 + (L>>4)*8 + j
//   k<48: W[k][col]; k==48: bias (paired with B=1.0); else 0.
// ---------------------------------------------------------------------------
__global__ void pack_W(const float* __restrict__ W, const float* __restrict__ b,
                       _Float16* __restrict__ WH) {
    int idx = blockIdx.x * 256 + threadIdx.x;     // < 73728
    int j    = idx & 7;
    int lane = (idx >> 3) & 63;
    int half = (idx >> 9) & 1;
    int tile = idx >> 10;        // 0..71 = g*NTILE + tau
    int tau  = tile % NTILE;
    int g    = tile / NTILE;
    int m  = lane & 15;
    int k  = half * 32 + ((lane >> 4) << 3) + j;
    int spline = g * 4 + (m >> 2);
    int param  = tau * 4 + (m & 3);
    float v = 0.0f;
    if (param < 33 && k <= 48) {
        int col = spline * 33 + param;
        v = (k < 48) ? W[k * 1056 + col] : b[col];
        if (param >= 17) v *= LOG2E;              // width columns: exp -> exp2
    }
    WH[idx] = (_Float16)v;
}

// pv[p] lives in the MFMA accumulators; indices are all compile-time.
#define PV(p) (acc[(p) >> 2][(p) & 3])
#define HP(i) ((i) < 16 ? hp2[(i) >> 1][(i) & 1] : hp16)
#define WD(i) (wd2[(i) >> 1][(i) & 1])
#define UN(i) ((i) < 16 ? un2[(i) >> 1][(i) & 1] : un16)

// ---------------------------------------------------------------------------
// R23 = R22 structure (proven-neutral vs R20's 43.8us; scalar arithmetic is
// exhausted) + PACKED-FP32 elementwise lanes: softplus poly / wd-normalize /
// sew tree / u-scale written as f32x2 so the backend can emit v_pk_fma_f32
// etc. (~75 fewer issue slots per task, -20% of VALU). Scan + selects stay
// scalar (serial); fallback branches stay per-element (R21b lesson). Pair
// formation is near-free: hp inputs PV(2j),PV(2j+1) are even-aligned acc
// register pairs. If the backend scalarizes, this is op-identical to R22.
// ---------------------------------------------------------------------------
__global__ void __launch_bounds__(256) fused_kernel(
    const float* __restrict__ z, const float* __restrict__ c,
    const _Float16* __restrict__ WH, float* __restrict__ out)
{
    const int tid  = threadIdx.x;
    const int w    = tid >> 6;
    const int lane = tid & 63;
    const int q    = lane >> 4;        // quad 0..3 = spline-sub within group
    const int cc   = lane & 15;        // row within wave
    const int row_base = blockIdx.x * BM + w * WROWS;

    // ---- z2 passthrough: out[:, :32] = z[:, 32:64] for this wave's rows ----
    #pragma unroll
    for (int it = 0; it < 2; ++it) {
        int idx = it * 64 + lane;                 // 0..127 = 16 rows x 8 float4
        int rr  = row_base + (idx >> 3);
        int v4  = idx & 7;
        float4 val = *(const float4*)(z + (size_t)rr * 64 + 32 + v4 * 4);
        *(float4*)(out + (size_t)rr * 64 + v4 * 4) = val;
    }

    // ---- z2c fragments (fp16, persist): the B operand ---------------------
    // B[k=(q*8+j)][n=cc] = z2c[row cc][k]
    half8 a0, a1;
    {
        const float* zr = z + (size_t)(row_base + cc) * 64 + 32;
        float4 v0 = *(const float4*)(zr + q * 8);
        float4 v1 = *(const float4*)(zr + q * 8 + 4);
        a0[0]=(_Float16)v0.x; a0[1]=(_Float16)v0.y;
        a0[2]=(_Float16)v0.z; a0[3]=(_Float16)v0.w;
        a0[4]=(_Float16)v1.x; a0[5]=(_Float16)v1.y;
        a0[6]=(_Float16)v1.z; a0[7]=(_Float16)v1.w;
        if (q < 2) {
            const float* cr = c + (size_t)(row_base + cc) * 16 + q * 8;
            float4 u0 = *(const float4*)cr;
            float4 u1 = *(const float4*)(cr + 4);
            a1[0]=(_Float16)u0.x; a1[1]=(_Float16)u0.y;
            a1[2]=(_Float16)u0.z; a1[3]=(_Float16)u0.w;
            a1[4]=(_Float16)u1.x; a1[5]=(_Float16)u1.y;
            a1[6]=(_Float16)u1.z; a1[7]=(_Float16)u1.w;
        } else {
            #pragma unroll
            for (int j = 0; j < 8; ++j) a1[j] = (_Float16)0.0f;
            if (q == 2) a1[0] = (_Float16)1.0f;   // k=48 bias row
        }
    }

    // z1 base for this lane's spline inputs: z[row cc][n = g*4 + q]
    const float* z1p = z + (size_t)(row_base + cc) * 64 + q;

    float ld_acc = 0.0f;   // accumulates log2 terms; scaled once at the end

    #pragma unroll 1
    for (int g = 0; g < NITER; ++g) {
        const float in = z1p[g * 4];        // hot L1 line

        // ---- GEMM: 9 tiles x (K=32 + K=16+bias) -> pv in registers --------
        floatx4 acc[NTILE];
        const half8* base = (const half8*)WH + (size_t)g * (NTILE * 2 * 64) + lane;
        #pragma unroll
        for (int t = 0; t < NTILE; ++t) {
            half8 w0 = base[(t * 2 + 0) * 64];
            half8 w1 = base[(t * 2 + 1) * 64];
            floatx4 a = {0.f, 0.f, 0.f, 0.f};
            a = __builtin_amdgcn_mfma_f32_16x16x32_f16(w0, a0, a, 0, 0, 0);
            a = __builtin_amdgcn_mfma_f32_16x16x32_f16(w1, a1, a, 0, 0, 0);
            acc[t] = a;
        }
        // lane (q,cc) now holds PV(p) = y[row cc][spline g*4+q][param p]
        // (width params 17..32 pre-scaled by log2e).

        // ---- spline on registers -----------------------------------------
        const int n = g * GROUP + q;

        // widths: scalar exp2 (trans has no pk form) into f32x2 storage;
        // packed tree-sum (7 pk adds + 1 scalar) + packed normalize (8 pk fma)
        f32x2 wd2[8];
        #pragma unroll
        for (int j = 0; j < 8; ++j) {
            wd2[j].x = __builtin_amdgcn_exp2f(PV(17 + 2 * j));
            wd2[j].y = __builtin_amdgcn_exp2f(PV(18 + 2 * j));
        }
        f32x2 sA = (wd2[0] + wd2[1]) + (wd2[2] + wd2[3]);
        f32x2 sB = (wd2[4] + wd2[5]) + (wd2[6] + wd2[7]);
        f32x2 sT = sA + sB;
        const float sew = sT.x + sT.y;
        const float inv_sew = 0.984f * __builtin_amdgcn_rcpf(sew);
        #pragma unroll
        for (int j = 0; j < 8; ++j) wd2[j] = wd2[j] * inv_sew + 0.001f;

        // heights: packed poly (even-aligned acc pairs), scalar 17th
        f32x2 hp2[8];
        #pragma unroll
        for (int j = 0; j < 8; ++j) {
            f32x2 t;
            t.x = PV(2 * j);
            t.y = PV(2 * j + 1);
            hp2[j] = softplus2(t);
        }
        const float hp16 = softplus1(PV(16));

        // S = sum (hp[i]+hp[i+1])*wd[i] (scalar serial, as R22)
        float S = 0.f;
        #pragma unroll
        for (int i = 0; i < 16; ++i) S = fmaf(HP(i) + HP(i + 1), WD(i), S);
        const float inv2 = 0.999f * __builtin_amdgcn_rcpf(S);
        // u = h_norm/2: packed scale (8 pk fma + 1 scalar)
        f32x2 un2[8];
        #pragma unroll
        for (int j = 0; j < 8; ++j) un2[j] = hp2[j] * inv2 + 0.0005f;
        const float un16 = fmaf(hp16, inv2, 0.0005f);

        // scan: scalar (serial dependence); element reads are subregisters
        float loc = 0.f, cdfl = 0.f;
        float sel_loc = 0.f, sel_w = WD(0), sel_cdf = 0.f;
        float sel_lu = UN(0), sel_ru = UN(1);
        #pragma unroll
        for (int bn = 1; bn < 16; ++bn) {
            cdfl = fmaf(UN(bn - 1) + UN(bn), WD(bn - 1), cdfl);
            loc += WD(bn - 1);
            if (in >= loc) {                        // monotone: last true wins
                sel_loc = loc; sel_w = WD(bn); sel_cdf = cdfl;
                sel_lu = UN(bn); sel_ru = UN(bn + 1);
            }
        }

        const float alpha = (in - sel_loc) * __builtin_amdgcn_rcpf(sel_w);
        const float du    = sel_ru - sel_lu;        // = dh/2
        const float lw    = sel_lu * sel_w;         // = lh*w/2
        // o = (0.5*dh*w)*a^2 + (lh*w)*a + cdf = ((du*w)*a + 2*lw)*a + cdf
        float o = fmaf(fmaf(du * sel_w, alpha, lw + lw), alpha, sel_cdf);
        o = fminf(fmaxf(o, 0.0f), 1.0f);
        out[(size_t)(row_base + cc) * 64 + 32 + n] = o;
        // ln(a*dh + lh) = LN2*(1 + log2(a*du + lu)); defer scale+offset
        ld_acc += __builtin_amdgcn_logf(fmaf(alpha, du, sel_lu));
    }

    // ---- logdet: lanes {cc, cc+16, cc+32, cc+48} hold row cc's partials ---
    ld_acc += __shfl_down(ld_acc, 32, 64);
    ld_acc += __shfl_down(ld_acc, 16, 64);
    if (q == 0)   // 32 log2-terms: ln2*(sum + 32)
        out[(size_t)M_ROWS * 64 + row_base + cc] =
            fmaf(ld_acc, LN2, 32.0f * LN2);
}

extern "C" void kernel_launch(void* const* d_in, const int* in_sizes, int n_in,
                              void* d_out, int out_size, void* d_ws, size_t ws_size,
                              hipStream_t stream) {
    const float* c = (const float*)d_in[0];   // (M, 16)
    const float* z = (const float*)d_in[1];   // (M, 64)
    const float* W = (const float*)d_in[2];   // (48, 1056)
    const float* b = (const float*)d_in[3];   // (1056,)
    float* out = (float*)d_out;               // M*64 (x) then M (logdet)
    _Float16* WH = (_Float16*)d_ws;           // 73728 fp16 = 144 KiB

    pack_W<<<WB_ELEMS / 256, 256, 0, stream>>>(W, b, WH);
    fused_kernel<<<M_ROWS / BM, 256, 0, stream>>>(z, c, WH, out);
}